// Round 1
// baseline (348.200 us; speedup 1.0000x reference)
//
#include <hip/hip_runtime.h>

// DWT front-end: 3-level db4 decomposition + per-band reconstruction.
// One block per row (B*C = 2048 rows of n=8192). All intermediates in LDS.
//
// Lengths: L1=4099, L2=2053, L3=1030  (L_out = (n+5)/2 + 1, symmetric pad).
// Single-band waverec collapses to chains of upsample-convs:
//   band a3: up_LO(up_LO(up_LO(a3)))   band d3: up_LO(up_LO(up_HI(d3)))
//   band d2: up_LO(up_HI(d2))          band d1: up_HI(d1)
// (with the waverec trim 2L-6 -> drop-last between stages)

#define T     256
#define N0    8192
#define L1    4099
#define L2    2053
#define L3    1030
#define NROWS 2048

// db4 REC_LO taps
#define RL0 0.23037781330885523f
#define RL1 0.7148465705525415f
#define RL2 0.6308807679295904f
#define RL3 (-0.02798376941698385f)
#define RL4 (-0.18703481171888114f)
#define RL5 0.030841381835986965f
#define RL6 0.032883011666982945f
#define RL7 (-0.010597401784997278f)

// Forward level: cA[i] = sum_t xe[2i+t]*REC_LO[t], cD likewise with REC_HI.
// xe = symmetric pad (7,7) then drop first => xe[j] = x[sym(j-6)].
__device__ __forceinline__ void fwd_level(const float* __restrict__ src, int n, int Lout,
                                          float* __restrict__ dstA, float* __restrict__ dstD,
                                          int tid)
{
    const float lo[8] = {RL0, RL1, RL2, RL3, RL4, RL5, RL6, RL7};
    const float hi[8] = {RL7, -RL6, RL5, -RL4, RL3, -RL2, RL1, -RL0}; // REC_HI[k]=(-1)^k*RL[7-k]
    for (int i = tid; i < Lout; i += T) {
        int j0 = 2 * i - 6;
        float sa = 0.f, sd = 0.f;
#pragma unroll
        for (int t = 0; t < 8; ++t) {
            int m = j0 + t;
            m = (m < 0) ? (-1 - m) : m;
            m = (m >= n) ? (2 * n - 1 - m) : m;
            float v = src[m];
            sa = fmaf(v, lo[t], sa);
            sd = fmaf(v, hi[t], sd);
        }
        dstA[i] = sa;
        dstD[i] = sd;
    }
}

// Upsample-conv (lhs_dilation=2, pad (1,1), 8 taps g):
//   out[2p]   = s[p]*g1 + s[p+1]*g3 + s[p+2]*g5 + s[p+3]*g7   (even taps e0..e3)
//   out[2p+1] = s[p]*g0 + s[p+1]*g2 + s[p+2]*g4 + s[p+3]*g6   (odd  taps o0..o3)
// out length 2L-6, p in [0, L-3). Indices never OOB.
__device__ __forceinline__ void upconv_mid(const float* __restrict__ s, float* __restrict__ dst,
                                           int L,
                                           float o0, float o1, float o2, float o3,
                                           float e0, float e1, float e2, float e3,
                                           int tid)
{
    for (int p = tid; p < L - 3; p += T) {
        float s0 = s[p], s1 = s[p + 1], s2 = s[p + 2], s3 = s[p + 3];
        float ev = s0 * e0 + s1 * e1 + s2 * e2 + s3 * e3;
        float od = s0 * o0 + s1 * o1 + s2 * o2 + s3 * o3;
        *(float2*)&dst[2 * p] = make_float2(ev, od);
    }
}

// Final stage: L=4099 -> 8192 outputs, float4 stores straight to global.
__device__ __forceinline__ void upconv_final(const float* __restrict__ s, float* __restrict__ gout,
                                             float o0, float o1, float o2, float o3,
                                             float e0, float e1, float e2, float e3,
                                             int tid)
{
    for (int q = tid; q < N0 / 4; q += T) {
        int p = 2 * q;
        float s0 = s[p], s1 = s[p + 1], s2 = s[p + 2], s3 = s[p + 3], s4 = s[p + 4];
        float4 o;
        o.x = s0 * e0 + s1 * e1 + s2 * e2 + s3 * e3;
        o.y = s0 * o0 + s1 * o1 + s2 * o2 + s3 * o3;
        o.z = s1 * e0 + s2 * e1 + s3 * e2 + s4 * e3;
        o.w = s1 * o0 + s2 * o1 + s3 * o2 + s4 * o3;
        ((float4*)gout)[q] = o;
    }
}

// LDS pool (floats), lifetime-overlapped:
//   [0,4100)      a1  -> later t2 (needs 4100)
//   [4100,8199)   d1  -> later a2 (2053) -> later t1 (2054)
//   [8199,10252)  d2
//   [10252,11282) a3
//   [11282,12312) d3
#define POOL_F 12312

__global__ __launch_bounds__(T) void wavelet_bands(const float* __restrict__ x,
                                                   float* __restrict__ out)
{
    __shared__ float buf[POOL_F];
    const int tid = threadIdx.x;
    const int row = blockIdx.x;

    float* a1 = buf;            // 4099 used (slot 4100)
    float* t2 = buf;            // 4100
    float* d1 = buf + 4100;     // 4099
    float* a2 = buf + 4100;     // 2053 (after d1 dead)
    float* t1 = buf + 4100;     // 2054 (after a2 dead)
    float* d2 = buf + 8199;     // 2053
    float* a3 = buf + 10252;    // 1030
    float* d3 = buf + 11282;    // 1030

    const float* xr = x + (size_t)row * N0;
    const size_t band = (size_t)NROWS * N0;
    float* o0 = out + (size_t)row * N0; // a3 band
    float* o1 = o0 + band;              // d3 band
    float* o2 = o0 + 2 * band;          // d2 band
    float* o3 = o0 + 3 * band;          // d1 band

    // DEC_LO taps: odd set (g0,g2,g4,g6) = RL7,RL5,RL3,RL1 ; even set (g1,g3,g5,g7) = RL6,RL4,RL2,RL0
    // DEC_HI taps: odd set = -RL0,-RL2,-RL4,-RL6 ; even set = RL1,RL3,RL5,RL7

    // Level 1 forward (reads global x, cached)
    fwd_level(xr, N0, L1, a1, d1, tid);
    __syncthreads();

    // Band d1: single up_HI straight to global
    upconv_final(d1, o3, -RL0, -RL2, -RL4, -RL6, RL1, RL3, RL5, RL7, tid);
    __syncthreads();

    // Level 2 forward (a2 overwrites d1 slot)
    fwd_level(a1, L1, L2, a2, d2, tid);
    __syncthreads();

    // Level 3 forward
    fwd_level(a2, L2, L3, a3, d3, tid);
    __syncthreads();

    // Band d2: t2 = up_HI(d2) [len 4100], then up_LO(t2[:4099]) -> global
    upconv_mid(d2, t2, L2, -RL0, -RL2, -RL4, -RL6, RL1, RL3, RL5, RL7, tid);
    __syncthreads();
    upconv_final(t2, o2, RL7, RL5, RL3, RL1, RL6, RL4, RL2, RL0, tid);
    __syncthreads();

    // Band a3: up_LO(a3) -> t1 [2054]; up_LO(t1[:2053]) -> t2 [4100]; up_LO(t2[:4099]) -> global
    upconv_mid(a3, t1, L3, RL7, RL5, RL3, RL1, RL6, RL4, RL2, RL0, tid);
    __syncthreads();
    upconv_mid(t1, t2, L2, RL7, RL5, RL3, RL1, RL6, RL4, RL2, RL0, tid);
    __syncthreads();
    upconv_final(t2, o0, RL7, RL5, RL3, RL1, RL6, RL4, RL2, RL0, tid);
    __syncthreads();

    // Band d3: up_HI(d3) -> t1; up_LO -> t2; up_LO -> global
    upconv_mid(d3, t1, L3, -RL0, -RL2, -RL4, -RL6, RL1, RL3, RL5, RL7, tid);
    __syncthreads();
    upconv_mid(t1, t2, L2, RL7, RL5, RL3, RL1, RL6, RL4, RL2, RL0, tid);
    __syncthreads();
    upconv_final(t2, o1, RL7, RL5, RL3, RL1, RL6, RL4, RL2, RL0, tid);
}

extern "C" void kernel_launch(void* const* d_in, const int* in_sizes, int n_in,
                              void* d_out, int out_size, void* d_ws, size_t ws_size,
                              hipStream_t stream)
{
    const float* x = (const float*)d_in[0];
    float* out = (float*)d_out;
    wavelet_bands<<<NROWS, T, 0, stream>>>(x, out);
}

// Round 2
// 317.505 us; speedup vs baseline: 1.0967x; 1.0967x over previous
//
#include <hip/hip_runtime.h>

// 3-level db4 band-split, one block per row, T=1024, all intermediates in LDS.
// R1: full-occupancy (2 blocks/CU x 16 waves = 32 waves/CU), paired outputs
// with float2 LDS reads, clamp-free interior paths, merged phases (7 barriers).

#define T     1024
#define N0    8192
#define L1    4099
#define L2    2053
#define L3    1030
#define NROWS 2048

#define RL0 0.23037781330885523f
#define RL1 0.7148465705525415f
#define RL2 0.6308807679295904f
#define RL3 (-0.02798376941698385f)
#define RL4 (-0.18703481171888114f)
#define RL5 0.030841381835986965f
#define RL6 0.032883011666982945f
#define RL7 (-0.010597401784997278f)

// ---- forward DWT: interior pairs (no clamps). Outputs i0=2t, i0+1 for
// t in [2, tHi). Window w = s[4t-6 .. 4t+3], 5x float2 (8B-aligned: 4t-6 even).
__device__ __forceinline__ void fwd_interior(const float* __restrict__ s, int tHi,
                                             float* __restrict__ dstA,
                                             float* __restrict__ dstD, int tid)
{
    const float lo[8] = {RL0, RL1, RL2, RL3, RL4, RL5, RL6, RL7};
    const float hi[8] = {RL7, -RL6, RL5, -RL4, RL3, -RL2, RL1, -RL0};
    const float2* s2 = (const float2*)s;
    for (int t = 2 + tid; t < tHi; t += T) {
        float2 w0 = s2[2 * t - 3], w1 = s2[2 * t - 2], w2 = s2[2 * t - 1],
               w3 = s2[2 * t],     w4 = s2[2 * t + 1];
        float w[10] = {w0.x, w0.y, w1.x, w1.y, w2.x, w2.y, w3.x, w3.y, w4.x, w4.y};
        float sa0 = 0.f, sd0 = 0.f, sa1 = 0.f, sd1 = 0.f;
#pragma unroll
        for (int k = 0; k < 8; ++k) {
            sa0 = fmaf(w[k],     lo[k], sa0);
            sd0 = fmaf(w[k],     hi[k], sd0);
            sa1 = fmaf(w[k + 2], lo[k], sa1);
            sd1 = fmaf(w[k + 2], hi[k], sd1);
        }
        ((float2*)dstA)[t] = make_float2(sa0, sa1);
        ((float2*)dstD)[t] = make_float2(sd0, sd1);
    }
}

// ---- forward DWT: edge outputs with symmetric clamp (i<4 or i>=2*tHi).
__device__ __forceinline__ void fwd_edges(const float* __restrict__ s, int n, int Lout, int tHi,
                                          float* __restrict__ dstA,
                                          float* __restrict__ dstD, int tid)
{
    const float lo[8] = {RL0, RL1, RL2, RL3, RL4, RL5, RL6, RL7};
    const float hi[8] = {RL7, -RL6, RL5, -RL4, RL3, -RL2, RL1, -RL0};
    const int ub = 2 * tHi;
    const int tot = 4 + (Lout - ub);
    if (tid < tot) {
        int i = (tid < 4) ? tid : ub + (tid - 4);
        int j0 = 2 * i - 6;
        float sa = 0.f, sd = 0.f;
#pragma unroll
        for (int t = 0; t < 8; ++t) {
            int m = j0 + t;
            m = (m < 0) ? (-1 - m) : m;
            m = (m >= n) ? (2 * n - 1 - m) : m;
            float v = s[m];
            sa = fmaf(v, lo[t], sa);
            sd = fmaf(v, hi[t], sd);
        }
        dstA[i] = sa;
        dstD[i] = sd;
    }
}

// ---- upsample-conv, LDS->LDS. 4 outputs per iter (p=2t,2t+1), float4 store.
__device__ __forceinline__ void upconv_mid(const float* __restrict__ s, float* __restrict__ dst,
                                           int L,
                                           float o0, float o1, float o2, float o3,
                                           float e0, float e1, float e2, float e3, int tid)
{
    const float2* s2 = (const float2*)s;
    const int cnt = L - 3, P2 = cnt >> 1;
    for (int t = tid; t < P2; t += T) {
        float2 u0 = s2[t], u1 = s2[t + 1];
        float s4 = s[2 * t + 4];
        float a0 = u0.x, a1 = u0.y, a2 = u1.x, a3 = u1.y;
        float ev0 = a0 * e0 + a1 * e1 + a2 * e2 + a3 * e3;
        float od0 = a0 * o0 + a1 * o1 + a2 * o2 + a3 * o3;
        float ev1 = a1 * e0 + a2 * e1 + a3 * e2 + s4 * e3;
        float od1 = a1 * o0 + a2 * o1 + a3 * o2 + s4 * o3;
        ((float4*)dst)[t] = make_float4(ev0, od0, ev1, od1);
    }
    if ((cnt & 1) && tid == 0) {           // tail p = L-4 (odd) when cnt odd
        int p = cnt - 1;
        float s0 = s[p], s1 = s[p + 1], sc = s[p + 2], s3 = s[p + 3];
        float ev = s0 * e0 + s1 * e1 + sc * e2 + s3 * e3;
        float od = s0 * o0 + s1 * o1 + sc * o2 + s3 * o3;
        *(float2*)&dst[2 * p] = make_float2(ev, od);
    }
}

// ---- final upsample-conv (L=4099 -> 8192), float4 stores to global.
__device__ __forceinline__ void upconv_final(const float* __restrict__ s, float* __restrict__ g,
                                             float o0, float o1, float o2, float o3,
                                             float e0, float e1, float e2, float e3, int tid)
{
    const float2* s2 = (const float2*)s;
    for (int q = tid; q < N0 / 4; q += T) {
        float2 u0 = s2[q], u1 = s2[q + 1];
        float s4 = s[2 * q + 4];
        float a0 = u0.x, a1 = u0.y, a2 = u1.x, a3 = u1.y;
        float4 o;
        o.x = a0 * e0 + a1 * e1 + a2 * e2 + a3 * e3;
        o.y = a0 * o0 + a1 * o1 + a2 * o2 + a3 * o3;
        o.z = a1 * e0 + a2 * e1 + a3 * e2 + s4 * e3;
        o.w = a1 * o0 + a2 * o1 + a3 * o2 + s4 * o3;
        ((float4*)g)[q] = o;
    }
}

// LDS pool (floats), offsets multiple of 4 for float4 alignment:
//   a1/t2: [0,4100)  d1: [4100,8200)  a2/t1: [8200,10256)
//   d2: [10256,12312)  a3: [12312,13344)  d3: [13344,14376)
#define POOL_F 14376

__global__ __launch_bounds__(T) void wavelet_bands(const float* __restrict__ x,
                                                   float* __restrict__ out)
{
    __shared__ float buf[POOL_F];
    const int tid = threadIdx.x;
    const int row = blockIdx.x;

    float* a1 = buf;
    float* t2 = buf;
    float* d1 = buf + 4100;
    float* a2 = buf + 8200;
    float* t1 = buf + 8200;
    float* d2 = buf + 10256;
    float* a3 = buf + 12312;
    float* d3 = buf + 13344;

    const float* xr = x + (size_t)row * N0;
    const size_t band = (size_t)NROWS * N0;
    float* o0 = out + (size_t)row * N0;  // a3 band
    float* o1 = o0 + band;               // d3
    float* o2 = o0 + 2 * band;           // d2
    float* o3 = o0 + 3 * band;           // d1

    // tap sets:  up_LO: odd {RL7,RL5,RL3,RL1}, even {RL6,RL4,RL2,RL0}
    //            up_HI: odd {-RL0,-RL2,-RL4,-RL6}, even {RL1,RL3,RL5,RL7}
    const int tHi1 = (N0 - 3) >> 2;   // 2047
    const int tHi2 = (L1 - 3) >> 2;   // 1024
    const int tHi3 = (L2 - 3) >> 2;   // 512

    // Phase A: level-1 forward from global
    fwd_interior(xr, tHi1, a1, d1, tid);
    fwd_edges(xr, N0, L1, tHi1, a1, d1, tid);
    __syncthreads();

    // Phase B: band d1 -> o3  ||  level-2 forward (a1 -> a2,d2)
    upconv_final(d1, o3, -RL0, -RL2, -RL4, -RL6, RL1, RL3, RL5, RL7, tid);
    fwd_interior(a1, tHi2, a2, d2, tid);
    fwd_edges(a1, L1, L2, tHi2, a2, d2, tid);
    __syncthreads();

    // Phase C: level-3 forward (a2 -> a3,d3)  ||  d2 stage1: up_HI(d2) -> t2
    fwd_interior(a2, tHi3, a3, d3, tid);
    fwd_edges(a2, L2, L3, tHi3, a3, d3, tid);
    upconv_mid(d2, t2, L2, -RL0, -RL2, -RL4, -RL6, RL1, RL3, RL5, RL7, tid);
    __syncthreads();

    // Phase D: band d2 -> o2  ||  a3 stage1: up_LO(a3) -> t1
    upconv_final(t2, o2, RL7, RL5, RL3, RL1, RL6, RL4, RL2, RL0, tid);
    upconv_mid(a3, t1, L3, RL7, RL5, RL3, RL1, RL6, RL4, RL2, RL0, tid);
    __syncthreads();

    // Phase E: a3 stage2: up_LO(t1) -> t2
    upconv_mid(t1, t2, L2, RL7, RL5, RL3, RL1, RL6, RL4, RL2, RL0, tid);
    __syncthreads();

    // Phase F: band a3 -> o0  ||  d3 stage1: up_HI(d3) -> t1
    upconv_final(t2, o0, RL7, RL5, RL3, RL1, RL6, RL4, RL2, RL0, tid);
    upconv_mid(d3, t1, L3, -RL0, -RL2, -RL4, -RL6, RL1, RL3, RL5, RL7, tid);
    __syncthreads();

    // Phase G: d3 stage2: up_LO(t1) -> t2
    upconv_mid(t1, t2, L2, RL7, RL5, RL3, RL1, RL6, RL4, RL2, RL0, tid);
    __syncthreads();

    // Phase H: band d3 -> o1
    upconv_final(t2, o1, RL7, RL5, RL3, RL1, RL6, RL4, RL2, RL0, tid);
}

extern "C" void kernel_launch(void* const* d_in, const int* in_sizes, int n_in,
                              void* d_out, int out_size, void* d_ws, size_t ws_size,
                              hipStream_t stream)
{
    const float* x = (const float*)d_in[0];
    float* out = (float*)d_out;
    wavelet_bands<<<NROWS, T, 0, stream>>>(x, out);
}